// Round 12
// baseline (480.959 us; speedup 1.0000x reference)
//
#include <hip/hip_runtime.h>
#include <hip/hip_bf16.h>

#define BB 128
#define TT 64
#define HH 512
#define VV 10000
#define VP 10048   // 157 * 64
#define NTILES 157
#define NCHUNK 16
#define TPC 10     // tiles per chunk (last chunk: 7)
#define NBLK 256   // k_scan grid size

typedef __attribute__((ext_vector_type(8))) __bf16 bf16x8;
typedef __attribute__((ext_vector_type(4))) float f32x4;
typedef unsigned short ushort_t;

__device__ __forceinline__ ushort_t f2bf(float x) {
  union { float f; unsigned u; } v; v.f = x;
  unsigned r = v.u + 0x7fffu + ((v.u >> 16) & 1u);
  return (ushort_t)(r >> 16);
}

__device__ __forceinline__ f32x4 mfma16(bf16x8 a, bf16x8 b, f32x4 c) {
  return __builtin_amdgcn_mfma_f32_16x16x32_bf16(a, b, c, 0, 0, 0);
}

__device__ __forceinline__ float fsig(float x) {
  return __builtin_amdgcn_rcpf(1.f + __expf(-x));
}
__device__ __forceinline__ float ftanh(float x) {
  return 1.f - 2.f * __builtin_amdgcn_rcpf(__expf(2.f * x) + 1.f);
}

// device-coherent (agent-scope) 16B load: bypasses the non-coherent per-XCD L2.
// Caller MUST s_waitcnt vmcnt(0) before use.
__device__ __forceinline__ bf16x8 load16_sc1(const ushort_t* p) {
  bf16x8 r;
  asm volatile("global_load_dwordx4 %0, %1, off sc1" : "=v"(r) : "v"(p) : "memory");
  return r;
}

// device-coherent 16B store: write-through past L2 to the coherent point.
__device__ __forceinline__ void store16B_sc1(ushort_t* p, bf16x8 v) {
  asm volatile("global_store_dwordx4 %0, %1, off sc1" :: "v"(p), "v"(v) : "memory");
}

// async global->LDS 16B copy (linear dest = wave base + lane*16)
__device__ __forceinline__ void glds16(const ushort_t* g, ushort_t* l) {
  __builtin_amdgcn_global_load_lds(
      (const __attribute__((address_space(1))) unsigned*)g,
      (__attribute__((address_space(3))) unsigned*)l, 16, 0, 0);
}

// ---- weight prep: W'[c'][k] bf16, k-contig, c' = unit*4 + gate.
//      COALESCED reads: tile 64 k x 64 contiguous source cols, LDS transpose,
//      write 128B k-runs per scattered c' row.
__global__ void k_trans_w(const float* __restrict__ Wx0, const float* __restrict__ Wh0,
                          const float* __restrict__ Wx1, const float* __restrict__ Wh1,
                          ushort_t* __restrict__ dst0, ushort_t* __restrict__ dst1) {
  __shared__ float tile[64][65];
  const int kt = blockIdx.x * 64;          // 0..960
  const int col0 = blockIdx.y * 64;        // source col base
  const float* Wx = blockIdx.z ? Wx1 : Wx0;
  const float* Wh = blockIdx.z ? Wh1 : Wh0;
  ushort_t* dst = blockIdx.z ? dst1 : dst0;
  const int tid = threadIdx.x;
  const int cl = tid & 63;
  const int col = col0 + cl;
#pragma unroll
  for (int r = 0; r < 16; ++r) {
    const int kl = r * 4 + (tid >> 6);
    const int k = kt + kl;
    tile[kl][cl] = (k < 512) ? Wx[k * 2048 + col] : Wh[(k - 512) * 2048 + col];
  }
  __syncthreads();
#pragma unroll
  for (int s = 0; s < 16; ++s) {
    const int idx = tid + s * 256;
    const int cl2 = idx >> 6, kl2 = idx & 63;
    const int col2 = col0 + cl2;
    const int cp = ((col2 & 511) << 2) | (col2 >> 9);   // c' = unit*4 + gate
    dst[(size_t)cp * 1024 + kt + kl2] = f2bf(tile[kl2][cl2]);
  }
}

// ---- softmax_w transpose: SWT[v][k'] = sw[k][v], bf16, PRE-SWIZZLED:
//      element (v,k) at k' = ((kb ^ (v&7))<<3) | (k&7), kb = k>>3.
__global__ void k_trans_sw(const float* __restrict__ sw, ushort_t* __restrict__ dst) {
  __shared__ float tile[64][65];
  const int kt = blockIdx.x * 64;     // 0..448
  const int vt = blockIdx.y * 64;
  const int tid = threadIdx.x;
  const int vl = tid & 63;
  const int v = vt + vl;
#pragma unroll
  for (int r = 0; r < 16; ++r) {
    const int kl = r * 4 + (tid >> 6);
    tile[vl][kl] = (v < VV) ? sw[(size_t)(kt + kl) * VV + v] : 0.f;
  }
  __syncthreads();
#pragma unroll
  for (int s = 0; s < 16; ++s) {
    const int idx = tid + s * 256;
    const int vl2 = idx >> 6, kl2 = idx & 63;
    const int k = kt + kl2;
    const int kb = k >> 3;
    const int kp = (((kb ^ (vl2 & 7)) << 3) | (k & 7));
    dst[(size_t)(vt + vl2) * 512 + kp] = f2bf(tile[vl2][kl2]);
  }
}

// ---- embedding gather (t-major rows) + zero h state buffers + zero barrier
__global__ void k_misc(const int* __restrict__ feat, const float* __restrict__ emb,
                       ushort_t* __restrict__ xb, ushort_t* __restrict__ h0,
                       ushort_t* __restrict__ h1, unsigned* __restrict__ bar) {
  const int stride = gridDim.x * blockDim.x;
  for (int e = blockIdx.x * blockDim.x + threadIdx.x; e < 8192 * 512; e += stride) {
    const int row = e >> 9;              // t*128 + b
    const int t = row >> 7, b = row & 127;
    const int f = feat[b * 64 + t];
    xb[e] = f2bf(emb[(size_t)f * 512 + (e & 511)]);
    if (e < 2 * 128 * 512) { h0[e] = 0; h1[e] = 0; }
    if (e < 1024) bar[e] = 0u;
  }
}

// ---- persistent cooperative LSTM scan (sc1 exchange, per-bquad barrier with
//      2-LEVEL ARRIVAL TREE, x-stage + x-MFMA inside the wait window).
// 256 blocks x 256 threads. layer = bid>>7; lb=bid&127: cblk=lb>>2, bquad=lb&3.
// Barrier group = 64 blocks sharing bquad. Arrival: 8 sub-counters (8 blocks
// each, own cache line) + root counter bumped by last-of-sub — cuts worst-case
// RMW serialization 64 -> ~16. Poll: single root gen word (R8-proven).
// Layout: root cnt bar[g*16]; gen bar[256+g*16]; sub cnt bar[512+(g*8+s)*16].
__global__ __launch_bounds__(256, 1) void k_scan(
    const ushort_t* __restrict__ xb, const ushort_t* __restrict__ W0t,
    const ushort_t* __restrict__ W1t, const float* __restrict__ b0,
    const float* __restrict__ b1, ushort_t* __restrict__ h0g,
    ushort_t* __restrict__ h1g, ushort_t* __restrict__ out1,
    const int* __restrict__ seqlen, unsigned* __restrict__ bar) {
  __shared__ ushort_t act[32 * 128 * 8];   // 32 b-rows x 128 kslots x 8 halfs = 64 KB
  __shared__ ushort_t hst[32][16];         // h-state staging for coalesced stores
  __shared__ ushort_t ost[32][16];         // out (masked h) staging, layer 1 only
  __shared__ int sl_sh[32];
  const int bid = blockIdx.x;
  const int layer = bid >> 7;
  const int lb = bid & 127;
  const int cblk = lb >> 2;                // 0..31
  const int bquad = lb & 3;                // 0..3
  const int grp = bid & 3;                 // barrier group = bquad
  const int sub = (bid >> 2) >> 3;         // sub-group 0..7 (8 blocks each)
  const int tid = threadIdx.x;
  const int w = tid >> 6;
  const int lane = tid & 63;
  const int fr = lane & 15;
  const int hi = lane >> 4;
  const int w4hi = w * 4 + hi;

  const ushort_t* Wt = layer ? W1t : W0t;
  const float* bias = layer ? b1 : b0;
  ushort_t* hbuf = layer ? h1g : h0g;
  unsigned* subcnt = bar + 512 + (grp * 8 + sub) * 16;
  unsigned* rootcnt = bar + grp * 16;
  unsigned* genp = bar + 256 + grp * 16;

  if (tid < 32) sl_sh[tid] = seqlen[bquad * 32 + tid];

  // W' frags: wave covers c' [cblk*64 + w*16, +16); lane row = fr, k = ks*32+hi*8
  bf16x8 wreg[32];
  {
    const ushort_t* wp = Wt + (size_t)(cblk * 64 + w * 16 + fr) * 1024 + hi * 8;
#pragma unroll
    for (int ks = 0; ks < 32; ++ks)
      wreg[ks] = *reinterpret_cast<const bf16x8*>(wp + ks * 32);
  }

  const int u = cblk * 16 + w4hi;          // lane's hidden unit
  const float bi = bias[u];
  const float bc = bias[512 + u];
  const float bf_ = bias[1024 + u];
  const float bo = bias[1536 + u];

  __syncthreads();
  const int sl0 = sl_sh[fr];               // b_0 = bquad*32 + fr
  const int sl1 = sl_sh[fr + 16];          // b_1 = b_0 + 16

  float c0s = 0.f, c1s = 0.f;              // cell state (per lane, per frag)
  float h0s = 0.f, h1s = 0.f;              // hidden state (per lane, per frag)

#pragma unroll 1
  for (int p = 0; p <= 64; ++p) {
    const int t = layer ? (p - 1) : p;
    const bool active = layer ? (p >= 1) : (p < 64);
    const unsigned target = (unsigned)(p + 1);

    f32x4 acc0 = (f32x4){0.f, 0.f, 0.f, 0.f};
    f32x4 acc1 = (f32x4){0.f, 0.f, 0.f, 0.f};

    // ==== barrier: drain stores, tree-arrive, x-stage + x-MFMA in wait window ====
    asm volatile("s_waitcnt vmcnt(0)" ::: "memory");  // drain sc1 h stores
    __syncthreads();
    if (tid == 0) {
      const unsigned old = __hip_atomic_fetch_add(subcnt, 1u,
                                                  __ATOMIC_RELAXED, __HIP_MEMORY_SCOPE_AGENT);
      if (old + 1 == 8u * target) {        // last of sub-group this phase
        const unsigned rold = __hip_atomic_fetch_add(rootcnt, 1u,
                                                     __ATOMIC_RELAXED, __HIP_MEMORY_SCOPE_AGENT);
        if (rold + 1 == 8u * target)       // last sub-group overall
          __hip_atomic_store(genp, target, __ATOMIC_RELAXED, __HIP_MEMORY_SCOPE_AGENT);
      }
    }
    // wait window: layer-0 stages x-half of act AND runs the x-part MFMAs
    if (layer == 0 && active) {
      const ushort_t* xsrc = xb + (size_t)t * 128 * 512;
#pragma unroll
      for (int i = 0; i < 8; ++i) {
        const int idx = i * 256 + tid;       // 0..2047
        const int b = idx >> 6;
        const int kp = idx & 63;
        const int kslot = (kp & 0x30) | ((kp & 15) ^ (b & 15));
        const ushort_t* s = xsrc + (size_t)(bquad * 32 + b) * 512 + (kslot << 3);
        *reinterpret_cast<bf16x8*>(&act[(b * 128 + kp) * 8]) =
            *reinterpret_cast<const bf16x8*>(s);
      }
      __syncthreads();   // x-half visible block-wide
#pragma unroll
      for (int ks = 0; ks < 16; ++ks) {    // x-part: kslot 0..63
        const int kslot = ks * 4 + hi;
        const int kp = (kslot & 0x70) | ((kslot & 15) ^ fr);
        const bf16x8 bf0 = *reinterpret_cast<const bf16x8*>(&act[(fr * 128 + kp) * 8]);
        const bf16x8 bf1 = *reinterpret_cast<const bf16x8*>(&act[((16 + fr) * 128 + kp) * 8]);
        acc0 = mfma16(wreg[ks], bf0, acc0);
        acc1 = mfma16(wreg[ks], bf1, acc1);
      }
    }
    if (tid == 0) {
      while (__hip_atomic_load(genp, __ATOMIC_RELAXED, __HIP_MEMORY_SCOPE_AGENT) < target)
        __builtin_amdgcn_s_sleep(1);
    }
    __syncthreads();
    // ==== end barrier ====

    if (active) {
      if (layer == 1) {
        // x-half = masked h0 state (parity p&1, written by L0 last phase) + h1-half
        bf16x8 tmp[16];
        const ushort_t* xsrc = h0g + (size_t)(p & 1) * 128 * 512;
        const ushort_t* hsrc = h1g + (size_t)(t & 1) * 128 * 512;
        int dsts[16];
#pragma unroll
        for (int i = 0; i < 8; ++i) {
          const int idx = i * 256 + tid;
          const int b = idx >> 6;
          const int kp = idx & 63;
          const int kslot = (kp & 0x30) | ((kp & 15) ^ (b & 15));
          tmp[i] = load16_sc1(xsrc + (size_t)(bquad * 32 + b) * 512 + (kslot << 3));
          dsts[i] = (b * 128 + kp) * 8;
        }
#pragma unroll
        for (int i = 0; i < 8; ++i) {
          const int idx = i * 256 + tid;
          const int b = idx >> 6;
          const int kp = 64 + (idx & 63);
          const int kslot = (kp & 0x70) | ((kp & 15) ^ (b & 15));
          tmp[8 + i] = load16_sc1(hsrc + (size_t)(bquad * 32 + b) * 512 + ((kslot - 64) << 3));
          dsts[8 + i] = (b * 128 + kp) * 8;
        }
        asm volatile("s_waitcnt vmcnt(0)" ::: "memory");
        __builtin_amdgcn_sched_barrier(0);
        const bf16x8 ZV = {};
#pragma unroll
        for (int i = 0; i < 8; ++i) {    // x-half: apply sequence mask (o0 semantics)
          const int b = (i * 256 + tid) >> 6;
          *reinterpret_cast<bf16x8*>(&act[dsts[i]]) = (t < sl_sh[b]) ? tmp[i] : ZV;
        }
#pragma unroll
        for (int i = 0; i < 8; ++i)
          *reinterpret_cast<bf16x8*>(&act[dsts[8 + i]]) = tmp[8 + i];
        __syncthreads();
        // full GEMM for layer 1 (x-half wasn't available pre-barrier)
#pragma unroll
        for (int ks = 0; ks < 32; ++ks) {
          const int kslot = ks * 4 + hi;
          const int kp = (kslot & 0x70) | ((kslot & 15) ^ fr);
          const bf16x8 bf0 = *reinterpret_cast<const bf16x8*>(&act[(fr * 128 + kp) * 8]);
          const bf16x8 bf1 = *reinterpret_cast<const bf16x8*>(&act[((16 + fr) * 128 + kp) * 8]);
          acc0 = mfma16(wreg[ks], bf0, acc0);
          acc1 = mfma16(wreg[ks], bf1, acc1);
        }
      } else {
        // h-half only (x-half staged + x-MFMAs done in the wait window), sc1
        bf16x8 tmp[8];
        const ushort_t* hsrc = h0g + (size_t)(t & 1) * 128 * 512;
        int dsts[8];
#pragma unroll
        for (int i = 0; i < 8; ++i) {
          const int idx = i * 256 + tid;
          const int b = idx >> 6;
          const int kp = 64 + (idx & 63);
          const int kslot = (kp & 0x70) | ((kp & 15) ^ (b & 15));
          tmp[i] = load16_sc1(hsrc + (size_t)(bquad * 32 + b) * 512 + ((kslot - 64) << 3));
          dsts[i] = (b * 128 + kp) * 8;
        }
        asm volatile("s_waitcnt vmcnt(0)" ::: "memory");
        __builtin_amdgcn_sched_barrier(0);
#pragma unroll
        for (int i = 0; i < 8; ++i)
          *reinterpret_cast<bf16x8*>(&act[dsts[i]]) = tmp[i];
        __syncthreads();
        // h-part only: kslot 64..127
#pragma unroll
        for (int ks = 16; ks < 32; ++ks) {
          const int kslot = ks * 4 + hi;
          const int kp = (kslot & 0x70) | ((kslot & 15) ^ fr);
          const bf16x8 bf0 = *reinterpret_cast<const bf16x8*>(&act[(fr * 128 + kp) * 8]);
          const bf16x8 bf1 = *reinterpret_cast<const bf16x8*>(&act[((16 + fr) * 128 + kp) * 8]);
          acc0 = mfma16(wreg[ks], bf0, acc0);
          acc1 = mfma16(wreg[ks], bf1, acc1);
        }
      }
      __syncthreads();

      // in-lane LSTM pointwise: acc regs = gates {i, cg, f, o} of unit u
      {
        const float si = fsig(acc0[0] + bi);
        const float tc = ftanh(acc0[1] + bc);
        const float sf = fsig(acc0[2] + bf_);
        const float so = fsig(acc0[3] + bo);
        const float cn = sf * c0s + si * tc;
        const float hn = so * ftanh(cn);
        const bool msk = t < sl0;
        if (msk) { c0s = cn; h0s = hn; }
        hst[fr][w4hi] = f2bf(h0s);
        if (layer) ost[fr][w4hi] = msk ? f2bf(hn) : (ushort_t)0;
      }
      {
        const float si = fsig(acc1[0] + bi);
        const float tc = ftanh(acc1[1] + bc);
        const float sf = fsig(acc1[2] + bf_);
        const float so = fsig(acc1[3] + bo);
        const float cn = sf * c1s + si * tc;
        const float hn = so * ftanh(cn);
        const bool msk = t < sl1;
        if (msk) { c1s = cn; h1s = hn; }
        hst[fr + 16][w4hi] = f2bf(h1s);
        if (layer) ost[fr + 16][w4hi] = msk ? f2bf(hn) : (ushort_t)0;
      }
      __syncthreads();

      // coalesced 16B stores: 64 threads cover the 32x16 tile (2 chunks/row)
      if (tid < 64) {
        const int bl = tid >> 1, hf = tid & 1;
        const size_t off = (size_t)(bquad * 32 + bl) * 512 + cblk * 16 + hf * 8;
        ushort_t* hp = hbuf + (size_t)((t + 1) & 1) * 128 * 512 + off;
        const bf16x8 hv = *reinterpret_cast<const bf16x8*>(&hst[bl][hf * 8]);
        store16B_sc1(hp, hv);
        if (layer) {
          const bf16x8 ovv = *reinterpret_cast<const bf16x8*>(&ost[bl][hf * 8]);
          *reinterpret_cast<bf16x8*>(out1 + (size_t)t * 128 * 512 + off) = ovv;
        }
      }
    }
  }
}

// ---- fused logits @ softmax_w + online log-softmax + xent partials.
// 1-D grid of 1024 blocks: chunk = bid & 15 (XCD-affinity: dispatch round-robins
// XCDs by bid % 8, so all blocks of chunk c land on XCD c&7 and the chunk's
// 643 KB SWT slice stays L2-resident), rowblk = bid >> 4.
__global__ __launch_bounds__(256, 2) void k_loss_gemm(
    const ushort_t* __restrict__ A, const ushort_t* __restrict__ SWTs,
    const float* __restrict__ sb, const int* __restrict__ labels,
    float* __restrict__ part) {
  __shared__ ushort_t Bl[2][32 * 512];  // 2 x 32KB (pre-swizzled data, linear copy)
  __shared__ float sbl[640];
  const int tid = threadIdx.x;
  const int lane = tid & 63;
  const int w = tid >> 6;
  const int fr = lane & 15;
  const int fk = (lane >> 4) << 3;
  const int chunk = blockIdx.x & 15;
  const int rowbase = (blockIdx.x >> 4) * 128 + w * 32;
  const int tile_lo = chunk * TPC;
  const int tile_hi = (tile_lo + TPC < NTILES) ? (tile_lo + TPC) : NTILES;
  const int nhalf = (tile_hi - tile_lo) * 2;

  // prologue: sb chunk -> LDS (zero-padded past VV)
  for (int i = tid; i < 640; i += 256) {
    const int v = chunk * 640 + i;
    sbl[i] = (v < VV) ? sb[v] : 0.f;
  }

  bf16x8 a[2][16];
#pragma unroll
  for (int rf = 0; rf < 2; ++rf) {
    const ushort_t* ap = A + (size_t)(rowbase + rf * 16 + fr) * 512 + fk;
#pragma unroll
    for (int ks = 0; ks < 16; ++ks) a[rf][ks] = *reinterpret_cast<const bf16x8*>(ap + ks * 32);
  }

  int lab[2][4];
  float m[2][4], l[2][4], ll[2][4];
#pragma unroll
  for (int rf = 0; rf < 2; ++rf)
#pragma unroll
    for (int r = 0; r < 4; ++r) {
      const int rg = rowbase + rf * 16 + ((lane >> 4) << 2) + r;
      lab[rf][r] = labels[(rg & 127) * 64 + (rg >> 7)];
      m[rf][r] = -3.0e38f; l[rf][r] = 0.f; ll[rf][r] = 0.f;
    }
  __syncthreads();   // drains prologue vmem; sbl visible; vmcnt clean slate

  // stage(buf, halfidx): 8 x glds16 per thread, linear copy of pre-swizzled SWT
#define STAGE(BUF, HIDX)                                                         \
  do {                                                                           \
    const size_t gbase = (size_t)(tile_lo * 2 + (HIDX)) * 32 * 512;              \
    _Pragma("unroll")                                                            \
    for (int i_ = 0; i_ < 8; ++i_) {                                             \
      glds16(SWTs + gbase + (size_t)(i_ * 256 + tid) * 8,                        \
             &Bl[BUF][i_ * 2048 + w * 512]);                                     \
    }                                                                            \
  } while (0)

  f32x4 acc[2][4];
  STAGE(0, 0);

#pragma unroll 1
  for (int idx = 0; idx < nhalf; ++idx) {
    const int cur = idx & 1;
    if (idx + 1 < nhalf) {
      STAGE(cur ^ 1, idx + 1);
      asm volatile("s_waitcnt vmcnt(8)" ::: "memory");   // current half resident
    } else {
      asm volatile("s_waitcnt vmcnt(0)" ::: "memory");
    }
    __builtin_amdgcn_s_barrier();
    __builtin_amdgcn_sched_barrier(0);

    if ((idx & 1) == 0) {
      acc[0][0] = (f32x4){0.f,0.f,0.f,0.f}; acc[0][1] = (f32x4){0.f,0.f,0.f,0.f};
      acc[1][0] = (f32x4){0.f,0.f,0.f,0.f}; acc[1][1] = (f32x4){0.f,0.f,0.f,0.f};
#pragma unroll
      for (int ks = 0; ks < 16; ++ks) {
#pragma unroll
        for (int j = 0; j < 2; ++j) {
          const int vloc = j * 16 + fr;
          const int kb = ks * 4 + (fk >> 3);
          const bf16x8 b = *reinterpret_cast<const bf16x8*>(
              &Bl[cur][vloc * 512 + ((kb ^ (vloc & 7)) << 3)]);
          acc[0][j] = mfma16(a[0][ks], b, acc[0][j]);
          acc[1][j] = mfma16(a[1][ks], b, acc[1][j]);
        }
      }
    } else {
      acc[0][2] = (f32x4){0.f,0.f,0.f,0.f}; acc[0][3] = (f32x4){0.f,0.f,0.f,0.f};
      acc[1][2] = (f32x4){0.f,0.f,0.f,0.f}; acc[1][3] = (f32x4){0.f,0.f,0.f,0.f};
#pragma unroll
      for (int ks = 0; ks < 16; ++ks) {
#pragma unroll
        for (int j = 0; j < 2; ++j) {
          const int vloc = j * 16 + fr;
          const int kb = ks * 4 + (fk >> 3);
          const bf16x8 b = *reinterpret_cast<const bf16x8*>(
              &Bl[cur][vloc * 512 + ((kb ^ (vloc & 7)) << 3)]);
          acc[0][2 + j] = mfma16(a[0][ks], b, acc[0][2 + j]);
          acc[1][2 + j] = mfma16(a[1][ks], b, acc[1][2 + j]);
        }
      }

      // ---- per-tile online-softmax epilogue (VALU + sbl LDS only)
      const int tl = idx >> 1;
      const int vb = (tile_lo + tl) * 64;
      float sbt[4]; bool vld[4];
#pragma unroll
      for (int cf = 0; cf < 4; ++cf) {
        const int v = vb + cf * 16 + fr;
        vld[cf] = v < VV;
        sbt[cf] = sbl[tl * 64 + cf * 16 + fr];
      }
#pragma unroll
      for (int rf = 0; rf < 2; ++rf)
#pragma unroll
        for (int r = 0; r < 4; ++r) {
          const float x0 = vld[0] ? acc[rf][0][r] + sbt[0] : -3.0e38f;
          const float x1 = vld[1] ? acc[rf][1][r] + sbt[1] : -3.0e38f;
          const float x2 = vld[2] ? acc[rf][2][r] + sbt[2] : -3.0e38f;
          const float x3 = vld[3] ? acc[rf][3][r] + sbt[3] : -3.0e38f;
          const float tm = fmaxf(fmaxf(x0, x1), fmaxf(x2, x3));
          if (tm > -1.0e37f) {
            const float mn = fmaxf(m[rf][r], tm);
            const float sc = __expf(m[rf][r] - mn);
            const float se = __expf(x0 - mn) + __expf(x1 - mn) +
                             __expf(x2 - mn) + __expf(x3 - mn);
            l[rf][r] = l[rf][r] * sc + se;
            m[rf][r] = mn;
          }
          const int lt = lab[rf][r] - vb;
          if (lt >= 0 && lt < 64 && fr == (lt & 15)) {
            const int cf = lt >> 4;
            ll[rf][r] += (cf == 0) ? x0 : (cf == 1) ? x1 : (cf == 2) ? x2 : x3;
          }
        }
    }
    __builtin_amdgcn_s_barrier();
  }
#undef STAGE

  // merge across the 16 lanes of each row group, write partials
#pragma unroll
  for (int rf = 0; rf < 2; ++rf)
#pragma unroll
    for (int r = 0; r < 4; ++r) {
      float mm = m[rf][r], lv = l[rf][r], lv2 = ll[rf][r];
#pragma unroll
      for (int sh = 1; sh < 16; sh <<= 1) {
        const float m2 = __shfl_xor(mm, sh, 64);
        const float l2 = __shfl_xor(lv, sh, 64);
        const float ll2 = __shfl_xor(lv2, sh, 64);
        const float mn = fmaxf(mm, m2);
        lv = lv * __expf(mm - mn) + l2 * __expf(m2 - mn);
        mm = mn;
        lv2 += ll2;
      }
      if (fr == 0) {
        const int rg = rowbase + rf * 16 + ((lane >> 4) << 2) + r;
        float* p = part + ((size_t)chunk * 8192 + rg) * 4;
        p[0] = mm; p[1] = lv; p[2] = lv2;
      }
    }
}

// ---- merge chunk partials -> xent per row
__global__ void k_loss_merge(const float* __restrict__ part, float* __restrict__ xent) {
  const int row = blockIdx.x * 256 + threadIdx.x;
  float m = -3.0e38f, l = 0.f, ll = 0.f;
#pragma unroll
  for (int c = 0; c < NCHUNK; ++c) {
    const float* p = part + ((size_t)c * 8192 + row) * 4;
    const float pm = p[0], pl = p[1], pll = p[2];
    const float mn = fmaxf(m, pm);
    l = l * __expf(m - mn) + pl * __expf(pm - mn);
    m = mn;
    ll += pll;
  }
  xent[row] = m + logf(l) - ll;
}

// ---- final masked sequence loss
__global__ void k_final(const float* __restrict__ xent, const float* __restrict__ mask,
                        float* __restrict__ out) {
  __shared__ float partial[4];
  const int lane = threadIdx.x & 63;
  const int w = threadIdx.x >> 6;
  float accT = 0.f;
  for (int i = 0; i < 16; ++i) {
    const int t = w * 16 + i;
    const float m1 = mask[lane * 64 + t];
    const float m2 = mask[(lane + 64) * 64 + t];
    float s = xent[t * 128 + lane] * m1 + xent[t * 128 + lane + 64] * m2;
    float sm = m1 + m2;
#pragma unroll
    for (int sh = 1; sh < 64; sh <<= 1) {
      s += __shfl_xor(s, sh, 64);
      sm += __shfl_xor(sm, sh, 64);
    }
    accT += s / (sm + 1e-12f);
  }
  if (lane == 0) partial[w] = accT;
  __syncthreads();
  if (threadIdx.x == 0)
    out[0] = (partial[0] + partial[1] + partial[2] + partial[3]) * (1.f / 64.f);
}

extern "C" void kernel_launch(void* const* d_in, const int* in_sizes, int n_in,
                              void* d_out, int out_size, void* d_ws, size_t ws_size,
                              hipStream_t stream) {
  const int* feat = (const int*)d_in[0];
  const int* labels = (const int*)d_in[1];
  const int* seqlen = (const int*)d_in[2];
  const float* seqmask = (const float*)d_in[3];
  const float* emb = (const float*)d_in[4];
  const float* W0x = (const float*)d_in[5];
  const float* W0h = (const float*)d_in[6];
  const float* b0 = (const float*)d_in[7];
  const float* W1x = (const float*)d_in[8];
  const float* W1h = (const float*)d_in[9];
  const float* b1 = (const float*)d_in[10];
  const float* sw = (const float*)d_in[11];
  const float* sbv = (const float*)d_in[12];

  ushort_t* W0t = (ushort_t*)d_ws;                       // 2048*1024 bf16
  ushort_t* W1t = W0t + (size_t)2048 * 1024;
  ushort_t* SWT = W1t + (size_t)2048 * 1024;             // 10048*512 (pre-swizzled)
  ushort_t* xb = SWT + (size_t)VP * 512;                 // [T*B][512]
  ushort_t* out1 = xb + (size_t)8192 * 512;              // [T*B][512]
  ushort_t* h0g = out1 + (size_t)8192 * 512;             // 2 x [128][512]
  ushort_t* h1g = h0g + (size_t)2 * 128 * 512;
  float* xent = (float*)(h1g + (size_t)2 * 128 * 512);
  float* part = xent + 8192;                             // [16][8192][4]
  unsigned* bar = (unsigned*)(part + (size_t)NCHUNK * 8192 * 4);

  k_trans_w<<<dim3(16, 32, 2), 256, 0, stream>>>(W0x, W0h, W1x, W1h, W0t, W1t);
  k_trans_sw<<<dim3(8, 157), 256, 0, stream>>>(sw, SWT);
  k_misc<<<4096, 256, 0, stream>>>(feat, emb, xb, h0g, h1g, bar);

  {
    const ushort_t* a0 = xb; const ushort_t* a1 = W0t; const ushort_t* a2 = W1t;
    const float* a3 = b0; const float* a4 = b1;
    ushort_t* a5 = h0g; ushort_t* a6 = h1g; ushort_t* a7 = out1;
    const int* a8 = seqlen; unsigned* a9 = bar;
    void* args[] = {(void*)&a0, (void*)&a1, (void*)&a2, (void*)&a3, (void*)&a4,
                    (void*)&a5, (void*)&a6, (void*)&a7, (void*)&a8, (void*)&a9};
    hipLaunchCooperativeKernel((const void*)k_scan, dim3(NBLK), dim3(256), args, 0, stream);
  }

  k_loss_gemm<<<dim3(1024), 256, 0, stream>>>(out1, SWT, sbv, labels, part);
  k_loss_merge<<<32, 256, 0, stream>>>(part, xent);
  k_final<<<1, 256, 0, stream>>>(xent, seqmask, (float*)d_out);
}

// Round 14
// 461.609 us; speedup vs baseline: 1.0419x; 1.0419x over previous
//
#include <hip/hip_runtime.h>
#include <hip/hip_bf16.h>

#define BB 128
#define TT 64
#define HH 512
#define VV 10000
#define VP 10048   // 157 * 64
#define NTILES 157
#define NCHUNK 16
#define TPC 10     // tiles per chunk (last chunk: 7)
#define NBLK 256   // k_scan grid size

typedef __attribute__((ext_vector_type(8))) __bf16 bf16x8;
typedef __attribute__((ext_vector_type(4))) float f32x4;
typedef unsigned short ushort_t;

__device__ __forceinline__ ushort_t f2bf(float x) {
  union { float f; unsigned u; } v; v.f = x;
  unsigned r = v.u + 0x7fffu + ((v.u >> 16) & 1u);
  return (ushort_t)(r >> 16);
}

__device__ __forceinline__ f32x4 mfma16(bf16x8 a, bf16x8 b, f32x4 c) {
  return __builtin_amdgcn_mfma_f32_16x16x32_bf16(a, b, c, 0, 0, 0);
}

__device__ __forceinline__ float fsig(float x) {
  return __builtin_amdgcn_rcpf(1.f + __expf(-x));
}
__device__ __forceinline__ float ftanh(float x) {
  return 1.f - 2.f * __builtin_amdgcn_rcpf(__expf(2.f * x) + 1.f);
}

// device-coherent (agent-scope) 16B load: bypasses the non-coherent per-XCD L2.
// Caller MUST s_waitcnt vmcnt(0) before use.
__device__ __forceinline__ bf16x8 load16_sc1(const ushort_t* p) {
  bf16x8 r;
  asm volatile("global_load_dwordx4 %0, %1, off sc1" : "=v"(r) : "v"(p) : "memory");
  return r;
}

// device-coherent 16B store: write-through past L2 to the coherent point.
__device__ __forceinline__ void store16B_sc1(ushort_t* p, bf16x8 v) {
  asm volatile("global_store_dwordx4 %0, %1, off sc1" :: "v"(p), "v"(v) : "memory");
}

// async global->LDS 16B copy (linear dest = wave base + lane*16)
__device__ __forceinline__ void glds16(const ushort_t* g, ushort_t* l) {
  __builtin_amdgcn_global_load_lds(
      (const __attribute__((address_space(1))) unsigned*)g,
      (__attribute__((address_space(3))) unsigned*)l, 16, 0, 0);
}

// ---- fused prep: one launch, three block-range roles.
//   [0,1024)      : W transpose  (coalesced reads; c' = unit*4 + gate, k-contig)
//   [1024,2280)   : softmax_w transpose, PRE-SWIZZLED k' = ((kb^(v&7))<<3)|(k&7)
//   [2280,3304)   : embedding gather (t-major) + zero h-state + zero barrier
__global__ __launch_bounds__(256) void k_prep(
    const float* __restrict__ Wx0, const float* __restrict__ Wh0,
    const float* __restrict__ Wx1, const float* __restrict__ Wh1,
    ushort_t* __restrict__ dst0, ushort_t* __restrict__ dst1,
    const float* __restrict__ sw, ushort_t* __restrict__ swt,
    const int* __restrict__ feat, const float* __restrict__ emb,
    ushort_t* __restrict__ xb, ushort_t* __restrict__ h0,
    ushort_t* __restrict__ h1, unsigned* __restrict__ bar) {
  __shared__ float tile[64][65];
  const int bid = blockIdx.x;
  const int tid = threadIdx.x;

  if (bid < 1024) {
    // ---- W transpose: tile 64 k x 64 contiguous source cols, LDS transpose
    const int kt = (bid & 15) * 64;            // 0..960
    const int col0 = ((bid >> 4) & 31) * 64;   // source col base
    const int z = bid >> 9;
    const float* Wx = z ? Wx1 : Wx0;
    const float* Wh = z ? Wh1 : Wh0;
    ushort_t* dst = z ? dst1 : dst0;
    const int cl = tid & 63;
    const int col = col0 + cl;
#pragma unroll
    for (int r = 0; r < 16; ++r) {
      const int kl = r * 4 + (tid >> 6);
      const int k = kt + kl;
      tile[kl][cl] = (k < 512) ? Wx[k * 2048 + col] : Wh[(k - 512) * 2048 + col];
    }
    __syncthreads();
#pragma unroll
    for (int s = 0; s < 16; ++s) {
      const int idx = tid + s * 256;
      const int cl2 = idx >> 6, kl2 = idx & 63;
      const int col2 = col0 + cl2;
      const int cp = ((col2 & 511) << 2) | (col2 >> 9);   // c' = unit*4 + gate
      dst[(size_t)cp * 1024 + kt + kl2] = f2bf(tile[kl2][cl2]);
    }
  } else if (bid < 2280) {
    // ---- softmax_w transpose (pre-swizzled)
    const int b = bid - 1024;
    const int kt = (b & 7) * 64;      // 0..448
    const int vt = (b >> 3) * 64;     // 157 tiles
    const int vl = tid & 63;
    const int v = vt + vl;
#pragma unroll
    for (int r = 0; r < 16; ++r) {
      const int kl = r * 4 + (tid >> 6);
      tile[vl][kl] = (v < VV) ? sw[(size_t)(kt + kl) * VV + v] : 0.f;
    }
    __syncthreads();
#pragma unroll
    for (int s = 0; s < 16; ++s) {
      const int idx = tid + s * 256;
      const int vl2 = idx >> 6, kl2 = idx & 63;
      const int k = kt + kl2;
      const int kb = k >> 3;
      const int kp = (((kb ^ (vl2 & 7)) << 3) | (k & 7));
      swt[(size_t)(vt + vl2) * 512 + kp] = f2bf(tile[vl2][kl2]);
    }
  } else {
    // ---- embedding gather + zero states + zero barrier
    const int b = bid - 2280;   // 0..1023
    for (int e = b * 256 + tid; e < 8192 * 512; e += 1024 * 256) {
      const int row = e >> 9;            // t*128 + bb
      const int t = row >> 7, bb = row & 127;
      const int f = feat[bb * 64 + t];
      xb[e] = f2bf(emb[(size_t)f * 512 + (e & 511)]);
      if (e < 2 * 128 * 512) { h0[e] = 0; h1[e] = 0; }
      if (e < 1024) bar[e] = 0u;
    }
  }
}

// ---- persistent cooperative LSTM scan (sc1 exchange, per-bquad counter barrier,
//      arrive-early + x-stage AND x-MFMA inside the wait window). R10-proven.
__global__ __launch_bounds__(256, 1) void k_scan(
    const ushort_t* __restrict__ xb, const ushort_t* __restrict__ W0t,
    const ushort_t* __restrict__ W1t, const float* __restrict__ b0,
    const float* __restrict__ b1, ushort_t* __restrict__ h0g,
    ushort_t* __restrict__ h1g, ushort_t* __restrict__ out1,
    const int* __restrict__ seqlen, unsigned* __restrict__ bar) {
  __shared__ ushort_t act[32 * 128 * 8];   // 32 b-rows x 128 kslots x 8 halfs = 64 KB
  __shared__ ushort_t hst[32][16];         // h-state staging for coalesced stores
  __shared__ ushort_t ost[32][16];         // out (masked h) staging, layer 1 only
  __shared__ int sl_sh[32];
  const int bid = blockIdx.x;
  const int layer = bid >> 7;
  const int lb = bid & 127;
  const int cblk = lb >> 2;                // 0..31
  const int bquad = lb & 3;                // 0..3
  const int grp = bid & 3;                 // barrier group = bquad
  const int tid = threadIdx.x;
  const int w = tid >> 6;
  const int lane = tid & 63;
  const int fr = lane & 15;
  const int hi = lane >> 4;
  const int w4hi = w * 4 + hi;

  const ushort_t* Wt = layer ? W1t : W0t;
  const float* bias = layer ? b1 : b0;
  ushort_t* hbuf = layer ? h1g : h0g;

  if (tid < 32) sl_sh[tid] = seqlen[bquad * 32 + tid];

  // W' frags: wave covers c' [cblk*64 + w*16, +16); lane row = fr, k = ks*32+hi*8
  bf16x8 wreg[32];
  {
    const ushort_t* wp = Wt + (size_t)(cblk * 64 + w * 16 + fr) * 1024 + hi * 8;
#pragma unroll
    for (int ks = 0; ks < 32; ++ks)
      wreg[ks] = *reinterpret_cast<const bf16x8*>(wp + ks * 32);
  }

  const int u = cblk * 16 + w4hi;          // lane's hidden unit
  const float bi = bias[u];
  const float bc = bias[512 + u];
  const float bf_ = bias[1024 + u];
  const float bo = bias[1536 + u];

  __syncthreads();
  const int sl0 = sl_sh[fr];               // b_0 = bquad*32 + fr
  const int sl1 = sl_sh[fr + 16];          // b_1 = b_0 + 16

  float c0s = 0.f, c1s = 0.f;              // cell state (per lane, per frag)
  float h0s = 0.f, h1s = 0.f;              // hidden state (per lane, per frag)

#pragma unroll 1
  for (int p = 0; p <= 64; ++p) {
    const int t = layer ? (p - 1) : p;
    const bool active = layer ? (p >= 1) : (p < 64);
    const unsigned target = (unsigned)(p + 1);

    f32x4 acc0 = (f32x4){0.f, 0.f, 0.f, 0.f};
    f32x4 acc1 = (f32x4){0.f, 0.f, 0.f, 0.f};

    // ==== barrier: drain stores, arrive, x-stage + x-MFMA in wait window ====
    asm volatile("s_waitcnt vmcnt(0)" ::: "memory");  // drain sc1 h stores
    __syncthreads();
    if (tid == 0) {
      const unsigned old = __hip_atomic_fetch_add(&bar[grp * 16], 1u,
                                                  __ATOMIC_RELAXED, __HIP_MEMORY_SCOPE_AGENT);
      if (old + 1 == 64u * target)
        __hip_atomic_store(&bar[256 + grp * 16], target, __ATOMIC_RELAXED,
                           __HIP_MEMORY_SCOPE_AGENT);
    }
    // wait window: layer-0 stages x-half of act AND runs the x-part MFMAs
    if (layer == 0 && active) {
      const ushort_t* xsrc = xb + (size_t)t * 128 * 512;
#pragma unroll
      for (int i = 0; i < 8; ++i) {
        const int idx = i * 256 + tid;       // 0..2047
        const int b = idx >> 6;
        const int kp = idx & 63;
        const int kslot = (kp & 0x30) | ((kp & 15) ^ (b & 15));
        const ushort_t* s = xsrc + (size_t)(bquad * 32 + b) * 512 + (kslot << 3);
        *reinterpret_cast<bf16x8*>(&act[(b * 128 + kp) * 8]) =
            *reinterpret_cast<const bf16x8*>(s);
      }
      __syncthreads();   // x-half visible block-wide
#pragma unroll
      for (int ks = 0; ks < 16; ++ks) {    // x-part: kslot 0..63
        const int kslot = ks * 4 + hi;
        const int kp = (kslot & 0x70) | ((kslot & 15) ^ fr);
        const bf16x8 bf0 = *reinterpret_cast<const bf16x8*>(&act[(fr * 128 + kp) * 8]);
        const bf16x8 bf1 = *reinterpret_cast<const bf16x8*>(&act[((16 + fr) * 128 + kp) * 8]);
        acc0 = mfma16(wreg[ks], bf0, acc0);
        acc1 = mfma16(wreg[ks], bf1, acc1);
      }
    }
    if (tid == 0) {
      while (__hip_atomic_load(&bar[256 + grp * 16], __ATOMIC_RELAXED,
                               __HIP_MEMORY_SCOPE_AGENT) < target)
        __builtin_amdgcn_s_sleep(1);
    }
    __syncthreads();
    // ==== end barrier ====

    if (active) {
      if (layer == 1) {
        // x-half = masked h0 state (parity p&1, written by L0 last phase) + h1-half
        bf16x8 tmp[16];
        const ushort_t* xsrc = h0g + (size_t)(p & 1) * 128 * 512;
        const ushort_t* hsrc = h1g + (size_t)(t & 1) * 128 * 512;
        int dsts[16];
#pragma unroll
        for (int i = 0; i < 8; ++i) {
          const int idx = i * 256 + tid;
          const int b = idx >> 6;
          const int kp = idx & 63;
          const int kslot = (kp & 0x30) | ((kp & 15) ^ (b & 15));
          tmp[i] = load16_sc1(xsrc + (size_t)(bquad * 32 + b) * 512 + (kslot << 3));
          dsts[i] = (b * 128 + kp) * 8;
        }
#pragma unroll
        for (int i = 0; i < 8; ++i) {
          const int idx = i * 256 + tid;
          const int b = idx >> 6;
          const int kp = 64 + (idx & 63);
          const int kslot = (kp & 0x70) | ((kp & 15) ^ (b & 15));
          tmp[8 + i] = load16_sc1(hsrc + (size_t)(bquad * 32 + b) * 512 + ((kslot - 64) << 3));
          dsts[8 + i] = (b * 128 + kp) * 8;
        }
        asm volatile("s_waitcnt vmcnt(0)" ::: "memory");
        __builtin_amdgcn_sched_barrier(0);
        const bf16x8 ZV = {};
#pragma unroll
        for (int i = 0; i < 8; ++i) {    // x-half: apply sequence mask (o0 semantics)
          const int b = (i * 256 + tid) >> 6;
          *reinterpret_cast<bf16x8*>(&act[dsts[i]]) = (t < sl_sh[b]) ? tmp[i] : ZV;
        }
#pragma unroll
        for (int i = 0; i < 8; ++i)
          *reinterpret_cast<bf16x8*>(&act[dsts[8 + i]]) = tmp[8 + i];
        __syncthreads();
        // full GEMM for layer 1 (x-half wasn't available pre-barrier)
#pragma unroll
        for (int ks = 0; ks < 32; ++ks) {
          const int kslot = ks * 4 + hi;
          const int kp = (kslot & 0x70) | ((kslot & 15) ^ fr);
          const bf16x8 bf0 = *reinterpret_cast<const bf16x8*>(&act[(fr * 128 + kp) * 8]);
          const bf16x8 bf1 = *reinterpret_cast<const bf16x8*>(&act[((16 + fr) * 128 + kp) * 8]);
          acc0 = mfma16(wreg[ks], bf0, acc0);
          acc1 = mfma16(wreg[ks], bf1, acc1);
        }
      } else {
        // h-half only (x-half staged + x-MFMAs done in the wait window), sc1
        bf16x8 tmp[8];
        const ushort_t* hsrc = h0g + (size_t)(t & 1) * 128 * 512;
        int dsts[8];
#pragma unroll
        for (int i = 0; i < 8; ++i) {
          const int idx = i * 256 + tid;
          const int b = idx >> 6;
          const int kp = 64 + (idx & 63);
          const int kslot = (kp & 0x70) | ((kp & 15) ^ (b & 15));
          tmp[i] = load16_sc1(hsrc + (size_t)(bquad * 32 + b) * 512 + ((kslot - 64) << 3));
          dsts[i] = (b * 128 + kp) * 8;
        }
        asm volatile("s_waitcnt vmcnt(0)" ::: "memory");
        __builtin_amdgcn_sched_barrier(0);
#pragma unroll
        for (int i = 0; i < 8; ++i)
          *reinterpret_cast<bf16x8*>(&act[dsts[i]]) = tmp[i];
        __syncthreads();
        // h-part only: kslot 64..127
#pragma unroll
        for (int ks = 16; ks < 32; ++ks) {
          const int kslot = ks * 4 + hi;
          const int kp = (kslot & 0x70) | ((kslot & 15) ^ fr);
          const bf16x8 bf0 = *reinterpret_cast<const bf16x8*>(&act[(fr * 128 + kp) * 8]);
          const bf16x8 bf1 = *reinterpret_cast<const bf16x8*>(&act[((16 + fr) * 128 + kp) * 8]);
          acc0 = mfma16(wreg[ks], bf0, acc0);
          acc1 = mfma16(wreg[ks], bf1, acc1);
        }
      }
      __syncthreads();

      // in-lane LSTM pointwise: acc regs = gates {i, cg, f, o} of unit u
      {
        const float si = fsig(acc0[0] + bi);
        const float tc = ftanh(acc0[1] + bc);
        const float sf = fsig(acc0[2] + bf_);
        const float so = fsig(acc0[3] + bo);
        const float cn = sf * c0s + si * tc;
        const float hn = so * ftanh(cn);
        const bool msk = t < sl0;
        if (msk) { c0s = cn; h0s = hn; }
        hst[fr][w4hi] = f2bf(h0s);
        if (layer) ost[fr][w4hi] = msk ? f2bf(hn) : (ushort_t)0;
      }
      {
        const float si = fsig(acc1[0] + bi);
        const float tc = ftanh(acc1[1] + bc);
        const float sf = fsig(acc1[2] + bf_);
        const float so = fsig(acc1[3] + bo);
        const float cn = sf * c1s + si * tc;
        const float hn = so * ftanh(cn);
        const bool msk = t < sl1;
        if (msk) { c1s = cn; h1s = hn; }
        hst[fr + 16][w4hi] = f2bf(h1s);
        if (layer) ost[fr + 16][w4hi] = msk ? f2bf(hn) : (ushort_t)0;
      }
      __syncthreads();

      // coalesced 16B stores: 64 threads cover the 32x16 tile (2 chunks/row)
      if (tid < 64) {
        const int bl = tid >> 1, hf = tid & 1;
        const size_t off = (size_t)(bquad * 32 + bl) * 512 + cblk * 16 + hf * 8;
        ushort_t* hp = hbuf + (size_t)((t + 1) & 1) * 128 * 512 + off;
        const bf16x8 hv = *reinterpret_cast<const bf16x8*>(&hst[bl][hf * 8]);
        store16B_sc1(hp, hv);
        if (layer) {
          const bf16x8 ovv = *reinterpret_cast<const bf16x8*>(&ost[bl][hf * 8]);
          *reinterpret_cast<bf16x8*>(out1 + (size_t)t * 128 * 512 + off) = ovv;
        }
      }
    }
  }
}

// ---- fused logits @ softmax_w + online log-softmax + xent partials.
// 1-D grid of 1024 blocks: chunk = bid & 15 (XCD-affinity: dispatch round-robins
// XCDs by bid % 8, so all blocks of chunk c land on XCD c&7 and the chunk's
// 643 KB SWT slice stays L2-resident), rowblk = bid >> 4.
__global__ __launch_bounds__(256, 2) void k_loss_gemm(
    const ushort_t* __restrict__ A, const ushort_t* __restrict__ SWTs,
    const float* __restrict__ sb, const int* __restrict__ labels,
    float* __restrict__ part) {
  __shared__ ushort_t Bl[2][32 * 512];  // 2 x 32KB (pre-swizzled data, linear copy)
  __shared__ float sbl[640];
  const int tid = threadIdx.x;
  const int lane = tid & 63;
  const int w = tid >> 6;
  const int fr = lane & 15;
  const int fk = (lane >> 4) << 3;
  const int chunk = blockIdx.x & 15;
  const int rowbase = (blockIdx.x >> 4) * 128 + w * 32;
  const int tile_lo = chunk * TPC;
  const int tile_hi = (tile_lo + TPC < NTILES) ? (tile_lo + TPC) : NTILES;
  const int nhalf = (tile_hi - tile_lo) * 2;

  // prologue: sb chunk -> LDS (zero-padded past VV)
  for (int i = tid; i < 640; i += 256) {
    const int v = chunk * 640 + i;
    sbl[i] = (v < VV) ? sb[v] : 0.f;
  }

  bf16x8 a[2][16];
#pragma unroll
  for (int rf = 0; rf < 2; ++rf) {
    const ushort_t* ap = A + (size_t)(rowbase + rf * 16 + fr) * 512 + fk;
#pragma unroll
    for (int ks = 0; ks < 16; ++ks) a[rf][ks] = *reinterpret_cast<const bf16x8*>(ap + ks * 32);
  }

  int lab[2][4];
  float m[2][4], l[2][4], ll[2][4];
#pragma unroll
  for (int rf = 0; rf < 2; ++rf)
#pragma unroll
    for (int r = 0; r < 4; ++r) {
      const int rg = rowbase + rf * 16 + ((lane >> 4) << 2) + r;
      lab[rf][r] = labels[(rg & 127) * 64 + (rg >> 7)];
      m[rf][r] = -3.0e38f; l[rf][r] = 0.f; ll[rf][r] = 0.f;
    }
  __syncthreads();   // drains prologue vmem; sbl visible; vmcnt clean slate

  // stage(buf, halfidx): 8 x glds16 per thread, linear copy of pre-swizzled SWT
#define STAGE(BUF, HIDX)                                                         \
  do {                                                                           \
    const size_t gbase = (size_t)(tile_lo * 2 + (HIDX)) * 32 * 512;              \
    _Pragma("unroll")                                                            \
    for (int i_ = 0; i_ < 8; ++i_) {                                             \
      glds16(SWTs + gbase + (size_t)(i_ * 256 + tid) * 8,                        \
             &Bl[BUF][i_ * 2048 + w * 512]);                                     \
    }                                                                            \
  } while (0)

  f32x4 acc[2][4];
  STAGE(0, 0);

#pragma unroll 1
  for (int idx = 0; idx < nhalf; ++idx) {
    const int cur = idx & 1;
    if (idx + 1 < nhalf) {
      STAGE(cur ^ 1, idx + 1);
      asm volatile("s_waitcnt vmcnt(8)" ::: "memory");   // current half resident
    } else {
      asm volatile("s_waitcnt vmcnt(0)" ::: "memory");
    }
    __builtin_amdgcn_s_barrier();
    __builtin_amdgcn_sched_barrier(0);

    if ((idx & 1) == 0) {
      acc[0][0] = (f32x4){0.f,0.f,0.f,0.f}; acc[0][1] = (f32x4){0.f,0.f,0.f,0.f};
      acc[1][0] = (f32x4){0.f,0.f,0.f,0.f}; acc[1][1] = (f32x4){0.f,0.f,0.f,0.f};
#pragma unroll
      for (int ks = 0; ks < 16; ++ks) {
#pragma unroll
        for (int j = 0; j < 2; ++j) {
          const int vloc = j * 16 + fr;
          const int kb = ks * 4 + (fk >> 3);
          const bf16x8 b = *reinterpret_cast<const bf16x8*>(
              &Bl[cur][vloc * 512 + ((kb ^ (vloc & 7)) << 3)]);
          acc[0][j] = mfma16(a[0][ks], b, acc[0][j]);
          acc[1][j] = mfma16(a[1][ks], b, acc[1][j]);
        }
      }
    } else {
      acc[0][2] = (f32x4){0.f,0.f,0.f,0.f}; acc[0][3] = (f32x4){0.f,0.f,0.f,0.f};
      acc[1][2] = (f32x4){0.f,0.f,0.f,0.f}; acc[1][3] = (f32x4){0.f,0.f,0.f,0.f};
#pragma unroll
      for (int ks = 0; ks < 16; ++ks) {
#pragma unroll
        for (int j = 0; j < 2; ++j) {
          const int vloc = j * 16 + fr;
          const int kb = ks * 4 + (fk >> 3);
          const bf16x8 b = *reinterpret_cast<const bf16x8*>(
              &Bl[cur][vloc * 512 + ((kb ^ (vloc & 7)) << 3)]);
          acc[0][2 + j] = mfma16(a[0][ks], b, acc[0][2 + j]);
          acc[1][2 + j] = mfma16(a[1][ks], b, acc[1][2 + j]);
        }
      }

      // ---- per-tile online-softmax epilogue (VALU + sbl LDS only)
      const int tl = idx >> 1;
      const int vb = (tile_lo + tl) * 64;
      float sbt[4]; bool vld[4];
#pragma unroll
      for (int cf = 0; cf < 4; ++cf) {
        const int v = vb + cf * 16 + fr;
        vld[cf] = v < VV;
        sbt[cf] = sbl[tl * 64 + cf * 16 + fr];
      }
#pragma unroll
      for (int rf = 0; rf < 2; ++rf)
#pragma unroll
        for (int r = 0; r < 4; ++r) {
          const float x0 = vld[0] ? acc[rf][0][r] + sbt[0] : -3.0e38f;
          const float x1 = vld[1] ? acc[rf][1][r] + sbt[1] : -3.0e38f;
          const float x2 = vld[2] ? acc[rf][2][r] + sbt[2] : -3.0e38f;
          const float x3 = vld[3] ? acc[rf][3][r] + sbt[3] : -3.0e38f;
          const float tm = fmaxf(fmaxf(x0, x1), fmaxf(x2, x3));
          if (tm > -1.0e37f) {
            const float mn = fmaxf(m[rf][r], tm);
            const float sc = __expf(m[rf][r] - mn);
            const float se = __expf(x0 - mn) + __expf(x1 - mn) +
                             __expf(x2 - mn) + __expf(x3 - mn);
            l[rf][r] = l[rf][r] * sc + se;
            m[rf][r] = mn;
          }
          const int lt = lab[rf][r] - vb;
          if (lt >= 0 && lt < 64 && fr == (lt & 15)) {
            const int cf = lt >> 4;
            ll[rf][r] += (cf == 0) ? x0 : (cf == 1) ? x1 : (cf == 2) ? x2 : x3;
          }
        }
    }
    __builtin_amdgcn_s_barrier();
  }
#undef STAGE

  // merge across the 16 lanes of each row group, write partials
#pragma unroll
  for (int rf = 0; rf < 2; ++rf)
#pragma unroll
    for (int r = 0; r < 4; ++r) {
      float mm = m[rf][r], lv = l[rf][r], lv2 = ll[rf][r];
#pragma unroll
      for (int sh = 1; sh < 16; sh <<= 1) {
        const float m2 = __shfl_xor(mm, sh, 64);
        const float l2 = __shfl_xor(lv, sh, 64);
        const float ll2 = __shfl_xor(lv2, sh, 64);
        const float mn = fmaxf(mm, m2);
        lv = lv * __expf(mm - mn) + l2 * __expf(m2 - mn);
        mm = mn;
        lv2 += ll2;
      }
      if (fr == 0) {
        const int rg = rowbase + rf * 16 + ((lane >> 4) << 2) + r;
        float* p = part + ((size_t)chunk * 8192 + rg) * 4;
        p[0] = mm; p[1] = lv; p[2] = lv2;
      }
    }
}

// ---- merge chunk partials -> xent per row
__global__ void k_loss_merge(const float* __restrict__ part, float* __restrict__ xent) {
  const int row = blockIdx.x * 256 + threadIdx.x;
  float m = -3.0e38f, l = 0.f, ll = 0.f;
#pragma unroll
  for (int c = 0; c < NCHUNK; ++c) {
    const float* p = part + ((size_t)c * 8192 + row) * 4;
    const float pm = p[0], pl = p[1], pll = p[2];
    const float mn = fmaxf(m, pm);
    l = l * __expf(m - mn) + pl * __expf(pm - mn);
    m = mn;
    ll += pll;
  }
  xent[row] = m + logf(l) - ll;
}

// ---- final masked sequence loss
__global__ void k_final(const float* __restrict__ xent, const float* __restrict__ mask,
                        float* __restrict__ out) {
  __shared__ float partial[4];
  const int lane = threadIdx.x & 63;
  const int w = threadIdx.x >> 6;
  float accT = 0.f;
  for (int i = 0; i < 16; ++i) {
    const int t = w * 16 + i;
    const float m1 = mask[lane * 64 + t];
    const float m2 = mask[(lane + 64) * 64 + t];
    float s = xent[t * 128 + lane] * m1 + xent[t * 128 + lane + 64] * m2;
    float sm = m1 + m2;
#pragma unroll
    for (int sh = 1; sh < 64; sh <<= 1) {
      s += __shfl_xor(s, sh, 64);
      sm += __shfl_xor(sm, sh, 64);
    }
    accT += s / (sm + 1e-12f);
  }
  if (lane == 0) partial[w] = accT;
  __syncthreads();
  if (threadIdx.x == 0)
    out[0] = (partial[0] + partial[1] + partial[2] + partial[3]) * (1.f / 64.f);
}

extern "C" void kernel_launch(void* const* d_in, const int* in_sizes, int n_in,
                              void* d_out, int out_size, void* d_ws, size_t ws_size,
                              hipStream_t stream) {
  const int* feat = (const int*)d_in[0];
  const int* labels = (const int*)d_in[1];
  const int* seqlen = (const int*)d_in[2];
  const float* seqmask = (const float*)d_in[3];
  const float* emb = (const float*)d_in[4];
  const float* W0x = (const float*)d_in[5];
  const float* W0h = (const float*)d_in[6];
  const float* b0 = (const float*)d_in[7];
  const float* W1x = (const float*)d_in[8];
  const float* W1h = (const float*)d_in[9];
  const float* b1 = (const float*)d_in[10];
  const float* sw = (const float*)d_in[11];
  const float* sbv = (const float*)d_in[12];

  ushort_t* W0t = (ushort_t*)d_ws;                       // 2048*1024 bf16
  ushort_t* W1t = W0t + (size_t)2048 * 1024;
  ushort_t* SWT = W1t + (size_t)2048 * 1024;             // 10048*512 (pre-swizzled)
  ushort_t* xb = SWT + (size_t)VP * 512;                 // [T*B][512]
  ushort_t* out1 = xb + (size_t)8192 * 512;              // [T*B][512]
  ushort_t* h0g = out1 + (size_t)8192 * 512;             // 2 x [128][512]
  ushort_t* h1g = h0g + (size_t)2 * 128 * 512;
  float* xent = (float*)(h1g + (size_t)2 * 128 * 512);
  float* part = xent + 8192;                             // [16][8192][4]
  unsigned* bar = (unsigned*)(part + (size_t)NCHUNK * 8192 * 4);

  k_prep<<<dim3(3304), 256, 0, stream>>>(W0x, W0h, W1x, W1h, W0t, W1t,
                                         sw, SWT, feat, emb, xb, h0g, h1g, bar);

  {
    const ushort_t* a0 = xb; const ushort_t* a1 = W0t; const ushort_t* a2 = W1t;
    const float* a3 = b0; const float* a4 = b1;
    ushort_t* a5 = h0g; ushort_t* a6 = h1g; ushort_t* a7 = out1;
    const int* a8 = seqlen; unsigned* a9 = bar;
    void* args[] = {(void*)&a0, (void*)&a1, (void*)&a2, (void*)&a3, (void*)&a4,
                    (void*)&a5, (void*)&a6, (void*)&a7, (void*)&a8, (void*)&a9};
    hipLaunchCooperativeKernel((const void*)k_scan, dim3(NBLK), dim3(256), args, 0, stream);
  }

  k_loss_gemm<<<dim3(1024), 256, 0, stream>>>(out1, SWT, sbv, labels, part);
  k_loss_merge<<<32, 256, 0, stream>>>(part, xent);
  k_final<<<1, 256, 0, stream>>>(xent, seqmask, (float*)d_out);
}